// Round 3
// baseline (146.463 us; speedup 1.0000x reference)
//
#include <hip/hip_runtime.h>
#include <hip/hip_bf16.h>
#include <stdint.h>

#define DIM 128
#define ODIM 64
#define BM 128
#define BN 64
#define NSPLIT 64

typedef __attribute__((ext_vector_type(8))) __bf16 bf16x8;
typedef __attribute__((ext_vector_type(4))) __bf16 bf16x4;
typedef __attribute__((ext_vector_type(2))) __bf16 bf16x2;
typedef __attribute__((ext_vector_type(4))) float f32x4;

#define MFMA_K32(a, b, c) __builtin_amdgcn_mfma_f32_16x16x32_bf16((a), (b), (c), 0, 0, 0)
#define MFMA_K16(a, b, c) __builtin_amdgcn_mfma_f32_16x16x16bf16_1k((a), (b), (c), 0, 0, 0)

// k = exp(-dist/(2*co)) = 2^(-sqrt(C2D*d2)), C2D = (log2e/(2*co))^2 pre-applied to x2/t2.
#define RBFD 10.077141124806595
#define LOG2E 1.4426950408889634
#define C2D ((LOG2E / (2.0 * RBFD)) * (LOG2E / (2.0 * RBFD)))

__device__ __forceinline__ void async_copy16(const void* g, void* l) {
  __builtin_amdgcn_global_load_lds((const __attribute__((address_space(1))) void*)g,
                                   (__attribute__((address_space(3))) void*)l, 16, 0, 0);
}
__device__ __forceinline__ void async_copy4(const void* g, void* l) {
  __builtin_amdgcn_global_load_lds((const __attribute__((address_space(1))) void*)g,
                                   (__attribute__((address_space(3))) void*)l, 4, 0, 0);
}

// round-to-nearest-ish bf16 pack: returns dword with lo16=bf16(a), hi16=bf16(b)
__device__ __forceinline__ uint32_t pack_bf16(float a, float b) {
  uint32_t ua = __builtin_bit_cast(uint32_t, a) + 0x8000u;
  uint32_t ub = __builtin_bit_cast(uint32_t, b) + 0x8000u;
  return __builtin_amdgcn_perm(ub, ua, 0x07060302u);
}

// ---- Fused prepass (one launch):
//   blocks [0, tB):        train rows -> bf16 + scaled row-norms (pad rows: 0 / 1e30)
//   blocks [tB, tB+fB):    feature rows -> bf16 + scaled row-norms
//   blocks [tB+fB, ...):   weights [N][64] fp32 -> Wt [64][Npad] bf16 (transpose)
__global__ void prep_all(const float* __restrict__ train, __bf16* __restrict__ Tb,
                         float* __restrict__ t2, const float* __restrict__ feat,
                         __bf16* __restrict__ Fb, float* __restrict__ x2,
                         const float* __restrict__ W, __bf16* __restrict__ Wt,
                         int Ntrain, int Npad, int nFeat, int tB, int fB, float scale) {
  __shared__ float tile[64][65];
  int b = blockIdx.x;
  int t = threadIdx.x;
  if (b < tB + fB) {
    const float* src;
    __bf16* dst;
    float* sq;
    int nValid, nPad, row0;
    float padv;
    if (b < tB) {
      src = train; dst = Tb; sq = t2; nValid = Ntrain; nPad = Npad; row0 = b * 4; padv = 1e30f;
    } else {
      src = feat; dst = Fb; sq = x2; nValid = nFeat; nPad = nFeat; row0 = (b - tB) * 4; padv = 0.0f;
    }
    int row = row0 + (t >> 6);
    int lane = t & 63;
    if (row >= nPad) return;
    float2 v = make_float2(0.0f, 0.0f);
    if (row < nValid) v = ((const float2*)src)[(size_t)row * 64 + lane];
    bf16x2 p;
    p.x = (__bf16)v.x;
    p.y = (__bf16)v.y;
    *(bf16x2*)&dst[(size_t)row * DIM + lane * 2] = p;
    float ss = v.x * v.x + v.y * v.y;
    #pragma unroll
    for (int off = 32; off > 0; off >>= 1) ss += __shfl_down(ss, off);
    if (lane == 0) sq[row] = (row < nValid) ? ss * scale : padv;
    return;
  }
  // ---- weight transpose tile
  int j0 = (b - tB - fB) * 64;
  int jr = t >> 2;
  int cg = (t & 3) * 16;
  int j = j0 + jr;
  if (j < Ntrain) {
    const float4* src = (const float4*)(W + (size_t)j * ODIM);
    #pragma unroll
    for (int q = 0; q < 4; ++q) {
      float4 u = src[(cg >> 2) + q];
      tile[jr][cg + q * 4 + 0] = u.x;
      tile[jr][cg + q * 4 + 1] = u.y;
      tile[jr][cg + q * 4 + 2] = u.z;
      tile[jr][cg + q * 4 + 3] = u.w;
    }
  } else {
    #pragma unroll
    for (int q = 0; q < 16; ++q) tile[jr][cg + q] = 0.0f;
  }
  __syncthreads();
  int v = t >> 2;
  int jc = (t & 3) * 16;
  __bf16 ob[16];
  #pragma unroll
  for (int q = 0; q < 16; ++q) ob[q] = (__bf16)tile[jc + q][v];
  __bf16* dst = Wt + (size_t)v * Npad + j0 + jc;
  *(bf16x8*)dst = *(bf16x8*)&ob[0];
  *(bf16x8*)(dst + 8) = *(bf16x8*)&ob[8];
}

// ---- Main fused kernel.
// S^T = T·F^T via mfma 16x16x32 (A = T-frags from sT, B = F-frags in regs).
// C-layout of S^T: lane(g4,l16) holds P[feat=l16][k=16mt+4g4+r] — exactly the
// A-operand layout of mfma 16x16x16 (A[m=lane&15][k=4*(lane>>4)+j], tile 16mt).
// So O += P·W chains from REGISTERS: no LDS round-trip for P at all.
template <bool ATOMIC>
__global__ __launch_bounds__(256, 4) void rbf_main(
    const __bf16* __restrict__ Fb, const __bf16* __restrict__ Tb,
    const __bf16* __restrict__ Wt, const float* __restrict__ t2g,
    const float* __restrict__ x2g, float* __restrict__ outOrPart,
    int nRows, int Npad, int nChunks) {
  __shared__ __bf16 sT[BN * DIM];   // 16 KB, XOR-swizzled 16B granules
  __shared__ __bf16 sW[ODIM * BN];  // 8 KB, XOR-swizzled 16B granules
  __shared__ float st2[BN];         // scaled t2 for this chunk

  const int tid = threadIdx.x;
  const int wave = tid >> 6;
  const int lane = tid & 63;
  const int l16 = lane & 15;
  const int g4 = lane >> 4;

  const int mb = (int)blockIdx.x;  // 0..15 (consecutive blocks share T chunks -> L2)
  const int ns = (int)blockIdx.y;  // 0..NSPLIT-1

  constexpr float KNEG2 = (float)(-2.0 * C2D);

  // F fragments (chunk-invariant): rows mb*128 + wave*32 + nf*16 + l16.
  bf16x8 bF[2][4];
  #pragma unroll
  for (int nf = 0; nf < 2; ++nf)
    #pragma unroll
    for (int ko = 0; ko < 4; ++ko)
      bF[nf][ko] = *(const bf16x8*)(Fb + ((size_t)(mb * BM + wave * 32 + nf * 16 + l16)) * DIM +
                                    ko * 32 + g4 * 8);

  float x2v[2];
  #pragma unroll
  for (int nf = 0; nf < 2; ++nf)
    x2v[nf] = x2g[mb * BM + wave * 32 + nf * 16 + l16];  // pre-scaled by C2D

  f32x4 zero4 = {0.0f, 0.0f, 0.0f, 0.0f};
  f32x4 oacc[2][4];
  #pragma unroll
  for (int nf = 0; nf < 2; ++nf)
    #pragma unroll
    for (int vi = 0; vi < 4; ++vi) oacc[nf][vi] = zero4;

  for (int c = ns; c < nChunks; c += NSPLIT) {
    const int n0 = c * BN;

    // Stage T chunk [64][128] bf16; LDS granule (row,g) holds global granule g^(row&15).
    {
      const char* gT = (const char*)Tb + (size_t)n0 * 256;
      #pragma unroll
      for (int i = 0; i < 4; ++i) {
        int off = i * 4096 + wave * 1024;  // wave-uniform LDS base
        int loff = off + lane * 16;
        int row = loff >> 8;
        int gran = (loff >> 4) & 15;
        async_copy16(gT + row * 256 + ((gran ^ (row & 15)) << 4), (char*)sT + off);
      }
    }
    // Stage W chunk: sW[v][0..63] = Wt[v][n0..n0+63]; granule g holds global g^(v&7).
    {
      #pragma unroll
      for (int i = 0; i < 2; ++i) {
        int off = i * 4096 + wave * 1024;
        int loff = off + lane * 16;
        int v = loff >> 7;
        int gran = (loff >> 4) & 7;
        const char* gW = (const char*)Wt + ((size_t)v * Npad + n0) * 2 + ((gran ^ (v & 7)) << 4);
        async_copy16(gW, (char*)sW + off);
      }
    }
    if (wave == 0) async_copy4((const char*)(t2g + n0) + lane * 4, (char*)st2);
    __syncthreads();

    // S^T per 16-train tile mt, then elementwise -> packed bf16 A-frags pk[mt][nf].
    uint2 pk[4][2];
    #pragma unroll
    for (int mt = 0; mt < 4; ++mt) {
      f32x4 s0 = zero4, s1 = zero4;
      #pragma unroll
      for (int ko = 0; ko < 4; ++ko) {
        int slot = (ko * 4 + g4) ^ l16;
        bf16x8 a = *(const bf16x8*)((const char*)sT + (mt * 16 + l16) * 256 + (slot << 4));
        s0 = MFMA_K32(a, bF[0][ko], s0);
        s1 = MFMA_K32(a, bF[1][ko], s1);
      }
      f32x4 t2v = *(const f32x4*)&st2[mt * 16 + g4 * 4];  // broadcast within 16-lane groups
      float kv0[4], kv1[4];
      #pragma unroll
      for (int r = 0; r < 4; ++r) {
        // d2 >= ~50 for this data (random normals, 128-dim); pads give +1e30 -> kv=0.
        float d20 = __builtin_fmaf(KNEG2, s0[r], t2v[r] + x2v[0]);
        float d21 = __builtin_fmaf(KNEG2, s1[r], t2v[r] + x2v[1]);
        kv0[r] = __builtin_amdgcn_exp2f(-__builtin_amdgcn_sqrtf(d20));
        kv1[r] = __builtin_amdgcn_exp2f(-__builtin_amdgcn_sqrtf(d21));
      }
      pk[mt][0] = make_uint2(pack_bf16(kv0[0], kv0[1]), pack_bf16(kv0[2], kv0[3]));
      pk[mt][1] = make_uint2(pack_bf16(kv1[0], kv1[1]), pack_bf16(kv1[2], kv1[3]));
    }

    // O += P·W via mfma 16x16x16: A = pk (registers!), B = b64 frags from sW.
    #pragma unroll
    for (int vi = 0; vi < 4; ++vi) {
      int rowB = (vi * 16 + l16) * 128 + ((g4 & 1) << 3);
      #pragma unroll
      for (int mt = 0; mt < 4; ++mt) {
        int gran = (2 * mt + (g4 >> 1)) ^ (l16 & 7);
        bf16x4 wf = *(const bf16x4*)((const char*)sW + rowB + (gran << 4));
        oacc[0][vi] = MFMA_K16(__builtin_bit_cast(bf16x4, pk[mt][0]), wf, oacc[0][vi]);
        oacc[1][vi] = MFMA_K16(__builtin_bit_cast(bf16x4, pk[mt][1]), wf, oacc[1][vi]);
      }
    }
    __syncthreads();  // protect sT/sW from next chunk's staging
  }

  if (ATOMIC) {
    float* out = outOrPart;
    #pragma unroll
    for (int nf = 0; nf < 2; ++nf)
      #pragma unroll
      for (int vi = 0; vi < 4; ++vi)
        #pragma unroll
        for (int r = 0; r < 4; ++r) {
          int row = mb * BM + wave * 32 + nf * 16 + g4 * 4 + r;
          int col = vi * 16 + l16;
          atomicAdd(&out[(size_t)row * ODIM + col], oacc[nf][vi][r]);
        }
  } else {
    float* dst = outOrPart + (size_t)ns * (size_t)nRows * ODIM;
    #pragma unroll
    for (int nf = 0; nf < 2; ++nf)
      #pragma unroll
      for (int vi = 0; vi < 4; ++vi)
        #pragma unroll
        for (int r = 0; r < 4; ++r) {
          int row = mb * BM + wave * 32 + nf * 16 + g4 * 4 + r;
          int col = vi * 16 + l16;
          dst[(size_t)row * ODIM + col] = oacc[nf][vi][r];
        }
  }
}

__global__ void reduce_parts(const float4* __restrict__ part, float4* __restrict__ out,
                             int total4) {
  int i = (int)blockIdx.x * blockDim.x + threadIdx.x;
  if (i >= total4) return;
  float4 s = make_float4(0.0f, 0.0f, 0.0f, 0.0f);
  #pragma unroll
  for (int sp = 0; sp < NSPLIT; ++sp) {
    float4 v = part[(size_t)sp * total4 + i];
    s.x += v.x; s.y += v.y; s.z += v.z; s.w += v.w;
  }
  out[i] = s;
}

extern "C" void kernel_launch(void* const* d_in, const int* in_sizes, int n_in,
                              void* d_out, int out_size, void* d_ws, size_t ws_size,
                              hipStream_t stream) {
  (void)n_in;
  const float* features = (const float*)d_in[0];
  const float* train = (const float*)d_in[1];
  const float* weights = (const float*)d_in[2];
  float* out = (float*)d_out;

  const int n = in_sizes[0] / DIM;        // 2048
  const int N = in_sizes[1] / DIM;        // 50000
  const int Npad = ((N + 63) / 64) * 64;  // 50048
  const int nChunks = Npad / 64;          // 782

  size_t off = 0;
  auto alloc = [&](size_t bytes) {
    size_t o = off;
    off = (off + bytes + 255) & ~(size_t)255;
    return o;
  };
  size_t oT = alloc((size_t)Npad * DIM * 2);
  size_t oW = alloc((size_t)ODIM * Npad * 2);
  size_t oF = alloc((size_t)n * DIM * 2);
  size_t ot2 = alloc((size_t)Npad * 4);
  size_t ox2 = alloc((size_t)n * 4);
  size_t oPart = alloc((size_t)NSPLIT * n * ODIM * 4);
  size_t needFull = off;

  char* ws = (char*)d_ws;
  __bf16* Tb = (__bf16*)(ws + oT);
  __bf16* Wt = (__bf16*)(ws + oW);
  __bf16* Fb = (__bf16*)(ws + oF);
  float* t2 = (float*)(ws + ot2);
  float* x2 = (float*)(ws + ox2);

  const int tB = Npad / 4;
  const int fB = n / 4;
  const int wB = Npad / 64;
  prep_all<<<tB + fB + wB, 256, 0, stream>>>(train, Tb, t2, features, Fb, x2, weights, Wt,
                                             N, Npad, n, tB, fB, (float)C2D);

  const int mBlocks = n / BM;      // 16
  dim3 grid(mBlocks, NSPLIT);      // 1024 blocks = 4/CU

  if (ws_size >= needFull) {
    float* part = (float*)(ws + oPart);
    rbf_main<false><<<grid, 256, 0, stream>>>(Fb, Tb, Wt, t2, x2, part, n, Npad, nChunks);
    int total4 = n * ODIM / 4;
    reduce_parts<<<(total4 + 255) / 256, 256, 0, stream>>>((const float4*)part, (float4*)out,
                                                           total4);
  } else {
    hipMemsetAsync(d_out, 0, (size_t)out_size * sizeof(float), stream);
    rbf_main<true><<<grid, 256, 0, stream>>>(Fb, Tb, Wt, t2, x2, out, n, Npad, nChunks);
  }
}